// Round 4
// baseline (604.379 us; speedup 1.0000x reference)
//
#include <hip/hip_runtime.h>
#include <hip/hip_bf16.h>
#include <cstdint>

typedef unsigned short u16;
typedef u16  u16x8 __attribute__((ext_vector_type(8)));
typedef short s16x8 __attribute__((ext_vector_type(8)));
typedef float f32x4 __attribute__((ext_vector_type(4)));

#define PI_F 3.14159265358979323846f
#define PD(i) ((i) + ((i) >> 5))

static __device__ __forceinline__ u16 f2bf(float f) {
    union { float f; unsigned u; } v; v.f = f;
    unsigned r = v.u + 0x7fffu + ((v.u >> 16) & 1u);
    return (u16)(r >> 16);
}
static __device__ __forceinline__ float bf2f(u16 h) {
    union { unsigned u; float f; } v; v.u = ((unsigned)h) << 16;
    return v.f;
}

__device__ __forceinline__ void gl_lds16(const u16* g, u16* l) {
    __builtin_amdgcn_global_load_lds(
        (const __attribute__((address_space(1))) unsigned int*)g,
        (__attribute__((address_space(3))) unsigned int*)l, 16, 0, 0);
}

// ---------------------------------------------------------------------------
// f32 -> bf16 convert (vectorized)
// ---------------------------------------------------------------------------
__global__ __launch_bounds__(256) void cvt_bf16(const float* __restrict__ in,
                                                u16* __restrict__ out, int n8) {
    int i = blockIdx.x * 256 + threadIdx.x;
    if (i >= n8) return;
    float4 a = ((const float4*)in)[2 * i];
    float4 b = ((const float4*)in)[2 * i + 1];
    u16x8 v;
    v[0] = f2bf(a.x); v[1] = f2bf(a.y); v[2] = f2bf(a.z); v[3] = f2bf(a.w);
    v[4] = f2bf(b.x); v[5] = f2bf(b.y); v[6] = f2bf(b.z); v[7] = f2bf(b.w);
    ((u16x8*)out)[i] = v;
}

// ---------------------------------------------------------------------------
// Expand quaternion weight W[4][512][in_q] into real matrix E[2048][4*in_q] bf16
// ---------------------------------------------------------------------------
__global__ void build_E(const float* __restrict__ W, u16* __restrict__ E, int logK) {
    const int K = 1 << logK;
    int idx = blockIdx.x * 256 + threadIdx.x;
    if (idx >= (2048 << logK)) return;
    int n = idx >> logK, k = idx & (K - 1);
    int o = n >> 2, c = n & 3, i = k >> 2, cp = k & 3;
    const int   qm[4][4] = {{0,1,2,3},{1,0,3,2},{2,3,0,1},{3,2,1,0}};
    const float qs[4][4] = {{1.f,-1.f,-1.f,-1.f},{1.f,1.f,1.f,-1.f},
                            {1.f,-1.f,1.f,1.f},{1.f,1.f,-1.f,1.f}};
    int in_q = K >> 2;
    float w = W[(size_t)qm[c][cp] * 512 * in_q + (size_t)o * in_q + i] * qs[c][cp];
    E[idx] = f2bf(w);
}

// ---------------------------------------------------------------------------
// bf16 MFMA GEMM, 256x256 tile, BK=64, 512 threads = 8 waves (2M x 4N).
// Per-wave output 128x64 (8x4 frags of 16x16x32). LDS 128 KiB: 2-slot dbuf.
// Phase-interleaved, counted vmcnt(2), raw s_barrier, T2 XOR swizzle.
// LDS layout: [256 rows][8 slots of 8 u16]; element slot s of row r lives at
// physical slot s ^ (r&7); staging pre-swizzles the GLOBAL source instead.
// OUTMODE 0: bf16 [m][n]; 1: f32 [m][n]; 2: bf16 transposed [b][n][s]
// ---------------------------------------------------------------------------
template<int K, int OUTMODE>
__global__ __launch_bounds__(512, 2) void gemm3(const u16* __restrict__ A,
                                                const u16* __restrict__ E,
                                                const float* __restrict__ bias,
                                                void* __restrict__ outp) {
    __shared__ u16 As[2][256 * 64];
    __shared__ u16 Bs[2][256 * 64];
    const int t    = threadIdx.x;            // 0..511
    const int lane = t & 63, wave = t >> 6;  // 8 waves
    const int wm   = wave >> 2, wn = wave & 3;
    const int lr   = lane & 15, kg = lane >> 4;
    const int l7   = lr & 7;
    const int m0   = blockIdx.y * 256;
    const int n0   = blockIdx.x * 256;
    constexpr int NT = K / 64;

    // staging geometry: chunk idx = t + q*512 -> row = idx>>3, slot = idx&7
    const int srow = t >> 3;                 // +q*64 per chunk q (q*64 % 8 == 0)
    const int sgsl = (t & 7) ^ (srow & 7);   // inverse-swizzled global k-group

    // swizzled read slot offsets (u16 units within a 64-u16 row)
    const int so0 = (kg ^ l7) * 8;           // ks=0
    const int so1 = ((4 + kg) ^ l7) * 8;     // ks=1

    f32x4 acc[8][4];
#pragma unroll
    for (int i = 0; i < 8; ++i)
#pragma unroll
        for (int j = 0; j < 4; ++j) acc[i][j] = (f32x4){0.f, 0.f, 0.f, 0.f};

#define STAGE(buf, v, q)                                                        \
    do {                                                                        \
        gl_lds16(A + (size_t)(m0 + srow + (q) * 64) * K + (v) * 64 + sgsl * 8,  \
                 &As[buf][(t + (q) * 512) * 8]);                                \
        gl_lds16(E + (size_t)(n0 + srow + (q) * 64) * K + (v) * 64 + sgsl * 8,  \
                 &Bs[buf][(t + (q) * 512) * 8]);                                \
    } while (0)

    // prologue: stage tile 0 fully (8 loads outstanding)
#pragma unroll
    for (int q = 0; q < 4; ++q) STAGE(0, 0, q);

#pragma unroll 1
    for (int v = 0; v < NT; ++v) {
        const int cur = v & 1, nxt = cur ^ 1;
        const u16* __restrict__ as = As[cur];
        const u16* __restrict__ bs = Bs[cur];

        __builtin_amdgcn_s_barrier();        // all waves done reading prev tile
        __builtin_amdgcn_sched_barrier(0);

        // ---- phase 0: stage q0 of next tile; sync tile-v data; ks=0, n0/n1
        if (v + 1 < NT) {
            STAGE(nxt, v + 1, 0);
            asm volatile("s_waitcnt vmcnt(2)" ::: "memory");
        } else {
            asm volatile("s_waitcnt vmcnt(0)" ::: "memory");
        }
        __builtin_amdgcn_s_barrier();        // everyone's tile-v loads landed
        __builtin_amdgcn_sched_barrier(0);

        s16x8 av[8], bv[2];
#pragma unroll
        for (int mi = 0; mi < 8; ++mi)
            av[mi] = *(const s16x8*)&as[(wm * 128 + mi * 16 + lr) * 64 + so0];
#pragma unroll
        for (int ni = 0; ni < 2; ++ni)
            bv[ni] = *(const s16x8*)&bs[(wn * 64 + ni * 16 + lr) * 64 + so0];
        __builtin_amdgcn_s_setprio(1);
#pragma unroll
        for (int mi = 0; mi < 8; ++mi)
#pragma unroll
            for (int ni = 0; ni < 2; ++ni)
                acc[mi][ni] = __builtin_amdgcn_mfma_f32_16x16x32_bf16(
                    av[mi], bv[ni], acc[mi][ni], 0, 0, 0);
        __builtin_amdgcn_s_setprio(0);
        __builtin_amdgcn_s_barrier();
        __builtin_amdgcn_sched_barrier(0);

        // ---- phase 1: stage q1; ks=0, n2/n3 (reuse av)
        if (v + 1 < NT) STAGE(nxt, v + 1, 1);
#pragma unroll
        for (int ni = 0; ni < 2; ++ni)
            bv[ni] = *(const s16x8*)&bs[(wn * 64 + (ni + 2) * 16 + lr) * 64 + so0];
        __builtin_amdgcn_s_setprio(1);
#pragma unroll
        for (int mi = 0; mi < 8; ++mi)
#pragma unroll
            for (int ni = 0; ni < 2; ++ni)
                acc[mi][ni + 2] = __builtin_amdgcn_mfma_f32_16x16x32_bf16(
                    av[mi], bv[ni], acc[mi][ni + 2], 0, 0, 0);
        __builtin_amdgcn_s_setprio(0);
        __builtin_amdgcn_s_barrier();
        __builtin_amdgcn_sched_barrier(0);

        // ---- phase 2: stage q2; ks=1, n0/n1
        if (v + 1 < NT) STAGE(nxt, v + 1, 2);
#pragma unroll
        for (int mi = 0; mi < 8; ++mi)
            av[mi] = *(const s16x8*)&as[(wm * 128 + mi * 16 + lr) * 64 + so1];
#pragma unroll
        for (int ni = 0; ni < 2; ++ni)
            bv[ni] = *(const s16x8*)&bs[(wn * 64 + ni * 16 + lr) * 64 + so1];
        __builtin_amdgcn_s_setprio(1);
#pragma unroll
        for (int mi = 0; mi < 8; ++mi)
#pragma unroll
            for (int ni = 0; ni < 2; ++ni)
                acc[mi][ni] = __builtin_amdgcn_mfma_f32_16x16x32_bf16(
                    av[mi], bv[ni], acc[mi][ni], 0, 0, 0);
        __builtin_amdgcn_s_setprio(0);
        __builtin_amdgcn_s_barrier();
        __builtin_amdgcn_sched_barrier(0);

        // ---- phase 3: stage q3; ks=1, n2/n3
        if (v + 1 < NT) STAGE(nxt, v + 1, 3);
#pragma unroll
        for (int ni = 0; ni < 2; ++ni)
            bv[ni] = *(const s16x8*)&bs[(wn * 64 + (ni + 2) * 16 + lr) * 64 + so1];
        __builtin_amdgcn_s_setprio(1);
#pragma unroll
        for (int mi = 0; mi < 8; ++mi)
#pragma unroll
            for (int ni = 0; ni < 2; ++ni)
                acc[mi][ni + 2] = __builtin_amdgcn_mfma_f32_16x16x32_bf16(
                    av[mi], bv[ni], acc[mi][ni + 2], 0, 0, 0);
        __builtin_amdgcn_s_setprio(0);
        // loop-top barrier closes phase 3
    }
#undef STAGE

    // epilogue
#pragma unroll
    for (int ni = 0; ni < 4; ++ni) {
        int n = n0 + wn * 64 + ni * 16 + lr;
        float bvl = bias[n];
#pragma unroll
        for (int mi = 0; mi < 8; ++mi) {
#pragma unroll
            for (int r = 0; r < 4; ++r) {
                int m = m0 + wm * 128 + mi * 16 + kg * 4 + r;
                float val = acc[mi][ni][r] + bvl;
                if constexpr (OUTMODE == 0) {
                    ((u16*)outp)[(size_t)m * 2048 + n] = f2bf(val);
                } else if constexpr (OUTMODE == 1) {
                    ((float*)outp)[(size_t)m * 2048 + n] = val;
                } else {
                    int b = m >> 11, s = m & 2047;
                    ((u16*)outp)[((size_t)b * 2048 + n) * 2048 + s] = f2bf(val);
                }
            }
        }
    }
}

// ---------------------------------------------------------------------------
// In-place radix-2 DIT FFT, 2048 complex in padded LDS (input bit-reversed).
// ---------------------------------------------------------------------------
__device__ __forceinline__ void bfly(float* re, float* im, int i0, int i1,
                                     float wr, float wi) {
    int p0 = PD(i0), p1 = PD(i1);
    float xr = re[p1], xi = im[p1];
    float tr = wr * xr - wi * xi;
    float ti = wr * xi + wi * xr;
    float yr = re[p0], yi = im[p0];
    re[p1] = yr - tr; im[p1] = yi - ti;
    re[p0] = yr + tr; im[p0] = yi + ti;
}

__device__ void fft2048(float* re, float* im, int t) {
#pragma unroll 1
    for (int lh = 0; lh < 9; ++lh) {
        const int half = 1 << lh;
        int j = t & (half - 1);
        float wr, wi;
        __sincosf((-PI_F / (float)half) * (float)j, &wi, &wr);
        __syncthreads();
#pragma unroll
        for (int u = 0; u < 4; ++u) {
            int bidx = t + u * 256;
            int i0 = ((bidx >> lh) << (lh + 1)) | j;
            bfly(re, im, i0, i0 + half, wr, wi);
        }
    }
#pragma unroll 1
    for (int lh = 9; lh < 11; ++lh) {
        const int half = 1 << lh;
        __syncthreads();
#pragma unroll
        for (int u = 0; u < 4; ++u) {
            int bidx = t + u * 256;
            int j = bidx & (half - 1);
            int i0 = ((bidx >> lh) << (lh + 1)) | j;
            float wr, wi;
            __sincosf((-PI_F / (float)half) * (float)j, &wi, &wr);
            bfly(re, im, i0, i0 + half, wr, wi);
        }
    }
    __syncthreads();
}

// ---------------------------------------------------------------------------
// Spectral attention: 2 channels/block, Q+iK packed forward FFTs (2),
// Hermitian-packed inverse (1). Vt multiplied in place.
// ---------------------------------------------------------------------------
__global__ __launch_bounds__(256) void spectral2(const u16* __restrict__ Qt,
                                                 const u16* __restrict__ Kt,
                                                 u16* __restrict__ Vt,
                                                 const float* __restrict__ alpha) {
    __shared__ float zre[2112], zim[2112];
    const int t  = threadIdx.x;
    const int b  = blockIdx.x >> 10;
    const int cp = blockIdx.x & 1023;
    const int c0 = cp * 2;
    const size_t base0 = ((size_t)b * 2048 + c0) * 2048;
    const size_t base1 = base0 + 2048;

    float ph[4];
    float PH1r[4], PH1i[4], PH2r[4], PH2i[4];
    float ph24 = 0.f, PH24_1 = 0.f, PH24_2 = 0.f;

#pragma unroll
    for (int ch = 0; ch < 2; ++ch) {
        const size_t base = ch ? base1 : base0;
        const u16* Qp = Qt + base;
        const u16* Kp = Kt + base;
        __syncthreads();
#pragma unroll
        for (int u = 0; u < 8; ++u) {
            int s = t + u * 256;
            int r = __brev((unsigned)s) >> 21;
            zre[PD(r)] = bf2f(Qp[s]);
            zim[PD(r)] = bf2f(Kp[s]);
        }
        fft2048(zre, zim, t);
        const float ac = alpha[c0 + ch];
#pragma unroll
        for (int u = 0; u < 4; ++u) {
            int k = t + u * 256;
            int m = (2048 - k) & 2047;
            float ar = zre[PD(k)], ai = zim[PD(k)];
            float br = zre[PD(m)], bi = zim[PD(m)];
            float qr = 0.5f * (ar + br), qi = 0.5f * (ai - bi);
            float kr = 0.5f * (ai + bi), ki = 0.5f * (br - ar);
            float cr = qr * kr + qi * ki;
            float ci = qi * kr - qr * ki;
            if (ch == 0) {
                int kk = min(k, 2048 - k);
                ph[u] = atanf(__logf((float)kk * (1.0f / 2048.0f) + 1e-6f));
            }
            float fr, fi;
            __sincosf(ph[u] * ac, &fi, &fr);
            float Pkr = cr * fr - ci * fi, Pki = cr * fi + ci * fr;
            float qr2 = 0.5f * (br + ar), qi2 = 0.5f * (bi - ai);
            float kr2 = 0.5f * (bi + ai), ki2 = 0.5f * (ar - br);
            float cr2 = qr2 * kr2 + qi2 * ki2;
            float ci2 = qi2 * kr2 - qr2 * ki2;
            float Pmr = cr2 * fr - ci2 * fi, Pmi = cr2 * fi + ci2 * fr;
            float hr = 0.5f * (Pkr + Pmr), hi = 0.5f * (Pki - Pmi);
            if (ch == 0) { PH1r[u] = hr; PH1i[u] = hi; }
            else         { PH2r[u] = hr; PH2i[u] = hi; }
        }
        if (t == 0) {
            float ar = zre[PD(1024)], ai = zim[PD(1024)];
            float cr = ar * ai;
            if (ch == 0) ph24 = atanf(__logf(0.5f + 1e-6f));
            float fr, fi;
            __sincosf(ph24 * ac, &fi, &fr);
            if (ch == 0) PH24_1 = cr * fr; else PH24_2 = cr * fr;
        }
    }

    __syncthreads();
#pragma unroll
    for (int u = 0; u < 4; ++u) {
        int k = t + u * 256;
        int m = (2048 - k) & 2047;
        int rk = __brev((unsigned)k) >> 21;
        int rm = __brev((unsigned)m) >> 21;
        zre[PD(rk)] = PH1r[u] - PH2i[u];
        zim[PD(rk)] = PH1i[u] + PH2r[u];
        zre[PD(rm)] = PH1r[u] + PH2i[u];
        zim[PD(rm)] = PH2r[u] - PH1i[u];
    }
    if (t == 0) {
        zre[PD(1)] = PH24_1;
        zim[PD(1)] = PH24_2;
    }
    fft2048(zre, zim, t);

#pragma unroll
    for (int u = 0; u < 8; ++u) {
        int s = t + u * 256;
        int j = (2048 - s) & 2047;
        float w0 = zre[PD(j)] * (1.0f / 2048.0f);
        float w1 = zim[PD(j)] * (1.0f / 2048.0f);
        Vt[base0 + s] = f2bf(bf2f(Vt[base0 + s]) * w0);
        Vt[base1 + s] = f2bf(bf2f(Vt[base1 + s]) * w1);
    }
}

// ---------------------------------------------------------------------------
// Transpose [B][C][S] bf16 -> [(b,s)][c] bf16
// ---------------------------------------------------------------------------
__global__ __launch_bounds__(256) void transpose_k(const u16* __restrict__ in,
                                                   u16* __restrict__ out) {
    __shared__ u16 tile[32][33];
    int b = blockIdx.z;
    int c0 = blockIdx.x * 32, s0 = blockIdx.y * 32;
    int tx = threadIdx.x, ty = threadIdx.y;
#pragma unroll
    for (int dy = 0; dy < 32; dy += 8)
        tile[ty + dy][tx] = in[((size_t)b * 2048 + c0 + ty + dy) * 2048 + s0 + tx];
    __syncthreads();
#pragma unroll
    for (int dy = 0; dy < 32; dy += 8)
        out[((size_t)b * 2048 + s0 + ty + dy) * 2048 + c0 + tx] = tile[tx][ty + dy];
}

// ---------------------------------------------------------------------------
extern "C" void kernel_launch(void* const* d_in, const int* in_sizes, int n_in,
                              void* d_out, int out_size, void* d_ws, size_t ws_size,
                              hipStream_t stream) {
    const float* query = (const float*)d_in[0];
    const float* key   = (const float*)d_in[1];
    const float* value = (const float*)d_in[2];
    const float* Wq    = (const float*)d_in[3];
    const float* bq    = (const float*)d_in[4];
    const float* Wk    = (const float*)d_in[5];
    const float* bk    = (const float*)d_in[6];
    const float* Wv    = (const float*)d_in[7];
    const float* bv    = (const float*)d_in[8];
    const float* alpha = (const float*)d_in[9];
    const float* Wint  = (const float*)d_in[10];
    const float* bint  = (const float*)d_in[11];
    const float* Wfin  = (const float*)d_in[12];
    const float* bfin  = (const float*)d_in[13];
    const float* Wout  = (const float*)d_in[14];
    const float* bout  = (const float*)d_in[15];

    char* ws = (char*)d_ws;
    size_t off = 0;
    auto alloc = [&](size_t bytes) -> void* {
        void* p = ws + off;
        off += (bytes + 255) & ~(size_t)255;
        return p;
    };
    u16* Eq   = (u16*)alloc((size_t)2048 * 512 * 2);
    u16* Ek   = (u16*)alloc((size_t)2048 * 512 * 2);
    u16* Ev   = (u16*)alloc((size_t)2048 * 512 * 2);
    u16* Eint = (u16*)alloc((size_t)2048 * 2048 * 2);
    u16* Efin = (u16*)alloc((size_t)2048 * 2048 * 2);
    u16* Eout = (u16*)alloc((size_t)2048 * 2048 * 2);
    u16* Qt   = (u16*)alloc((size_t)4 * 2048 * 2048 * 2);  // [B][C][S]
    u16* Kt   = (u16*)alloc((size_t)4 * 2048 * 2048 * 2);
    u16* Vt   = (u16*)alloc((size_t)4 * 2048 * 2048 * 2);
    u16* attn = (u16*)alloc((size_t)8192 * 2048 * 2);
    u16* h1   = Qt;
    u16* h2   = Kt;
    u16* Aq = attn;
    u16* Ak = attn + (size_t)8192 * 512;
    u16* Av = attn + (size_t)8192 * 1024;

    const int n8 = 8192 * 512 / 8;
    cvt_bf16<<<(n8 + 255) / 256, 256, 0, stream>>>(query, Aq, n8);
    cvt_bf16<<<(n8 + 255) / 256, 256, 0, stream>>>(key,   Ak, n8);
    cvt_bf16<<<(n8 + 255) / 256, 256, 0, stream>>>(value, Av, n8);

    build_E<<<(2048 * 512  + 255) / 256, 256, 0, stream>>>(Wq,   Eq,   9);
    build_E<<<(2048 * 512  + 255) / 256, 256, 0, stream>>>(Wk,   Ek,   9);
    build_E<<<(2048 * 512  + 255) / 256, 256, 0, stream>>>(Wv,   Ev,   9);
    build_E<<<(2048 * 2048 + 255) / 256, 256, 0, stream>>>(Wint, Eint, 11);
    build_E<<<(2048 * 2048 + 255) / 256, 256, 0, stream>>>(Wfin, Efin, 11);
    build_E<<<(2048 * 2048 + 255) / 256, 256, 0, stream>>>(Wout, Eout, 11);

    dim3 g3(8, 32);   // N/256, M/256
    gemm3<512, 2><<<g3, 512, 0, stream>>>(Aq, Eq, bq, Qt);
    gemm3<512, 2><<<g3, 512, 0, stream>>>(Ak, Ek, bk, Kt);
    gemm3<512, 2><<<g3, 512, 0, stream>>>(Av, Ev, bv, Vt);

    spectral2<<<4096, 256, 0, stream>>>(Qt, Kt, Vt, alpha);

    dim3 gt(64, 64, 4);
    transpose_k<<<gt, dim3(32, 8), 0, stream>>>(Vt, attn);

    gemm3<2048, 0><<<g3, 512, 0, stream>>>(attn, Eint, bint, h1);
    gemm3<2048, 0><<<g3, 512, 0, stream>>>(h1,   Efin, bfin, h2);
    gemm3<2048, 1><<<g3, 512, 0, stream>>>(h2,   Eout, bout, (float*)d_out);
}

// Round 5
// 572.496 us; speedup vs baseline: 1.0557x; 1.0557x over previous
//
#include <hip/hip_runtime.h>
#include <hip/hip_bf16.h>
#include <cstdint>

typedef unsigned short u16;
typedef u16  u16x8 __attribute__((ext_vector_type(8)));
typedef short s16x8 __attribute__((ext_vector_type(8)));
typedef float f32x4 __attribute__((ext_vector_type(4)));

#define PI_F 3.14159265358979323846f
#define PD(i) ((i) + ((i) >> 5))

static __device__ __forceinline__ u16 f2bf(float f) {
    union { float f; unsigned u; } v; v.f = f;
    unsigned r = v.u + 0x7fffu + ((v.u >> 16) & 1u);
    return (u16)(r >> 16);
}
static __device__ __forceinline__ float bf2f(u16 h) {
    union { unsigned u; float f; } v; v.u = ((unsigned)h) << 16;
    return v.f;
}

__device__ __forceinline__ void gl_lds16(const u16* g, u16* l) {
    __builtin_amdgcn_global_load_lds(
        (const __attribute__((address_space(1))) unsigned int*)g,
        (__attribute__((address_space(3))) unsigned int*)l, 16, 0, 0);
}

// ---------------------------------------------------------------------------
// f32 -> bf16 convert (vectorized)
// ---------------------------------------------------------------------------
__global__ __launch_bounds__(256) void cvt_bf16(const float* __restrict__ in,
                                                u16* __restrict__ out, int n8) {
    int i = blockIdx.x * 256 + threadIdx.x;
    if (i >= n8) return;
    float4 a = ((const float4*)in)[2 * i];
    float4 b = ((const float4*)in)[2 * i + 1];
    u16x8 v;
    v[0] = f2bf(a.x); v[1] = f2bf(a.y); v[2] = f2bf(a.z); v[3] = f2bf(a.w);
    v[4] = f2bf(b.x); v[5] = f2bf(b.y); v[6] = f2bf(b.z); v[7] = f2bf(b.w);
    ((u16x8*)out)[i] = v;
}

// ---------------------------------------------------------------------------
// Expand quaternion weight W[4][512][in_q] into real matrix E[2048][4*in_q] bf16
// ---------------------------------------------------------------------------
__global__ void build_E(const float* __restrict__ W, u16* __restrict__ E, int logK) {
    const int K = 1 << logK;
    int idx = blockIdx.x * 256 + threadIdx.x;
    if (idx >= (2048 << logK)) return;
    int n = idx >> logK, k = idx & (K - 1);
    int o = n >> 2, c = n & 3, i = k >> 2, cp = k & 3;
    const int   qm[4][4] = {{0,1,2,3},{1,0,3,2},{2,3,0,1},{3,2,1,0}};
    const float qs[4][4] = {{1.f,-1.f,-1.f,-1.f},{1.f,1.f,1.f,-1.f},
                            {1.f,-1.f,1.f,1.f},{1.f,1.f,-1.f,1.f}};
    int in_q = K >> 2;
    float w = W[(size_t)qm[c][cp] * 512 * in_q + (size_t)o * in_q + i] * qs[c][cp];
    E[idx] = f2bf(w);
}

// ---------------------------------------------------------------------------
// bf16 MFMA GEMM v4: 256x256 tile, BK=32, 512 threads = 8 waves (2M x 4N).
// 4-slot LDS ring (4 x 32 KiB), prefetch depth 3 -> issue-to-wait ~3 tiles
// (~1000+ cy) covers HBM latency. Per tile: 4 gl_lds/thread, vmcnt(10) once,
// 2 raw barriers, 32 MFMA in 2 clusters under setprio(1).
// vmcnt proof: at tile v's wait, issued = 12 + 4v + 2; vmcnt(10) retires
// through load #(4v+4) = tile v's last load. Tail stages clamped tiles into
// the dead slot to keep the count uniform.
// Swizzle: element (row, chunk c) at physical chunk c^(row&3); staging
// pre-swizzles the per-lane global source; reads use kg^(lr&3) (2-way, free).
// OUTMODE 0: bf16 [m][n]; 1: f32 [m][n]; 2: bf16 transposed [b][n][s]
// ---------------------------------------------------------------------------
template<int K, int OUTMODE>
__global__ __launch_bounds__(512, 2) void gemm4(const u16* __restrict__ A,
                                                const u16* __restrict__ E,
                                                const float* __restrict__ bias,
                                                void* __restrict__ outp) {
    __shared__ u16 As[4][256 * 32];
    __shared__ u16 Bs[4][256 * 32];
    const int t    = threadIdx.x;            // 0..511
    const int lane = t & 63, wave = t >> 6;  // 8 waves
    const int wm   = wave >> 2, wn = wave & 3;
    const int lr   = lane & 15, kg = lane >> 4;
    const int m0   = blockIdx.y * 256;
    const int n0   = blockIdx.x * 256;
    constexpr int NT = K / 32;

    // staging: idx = t + j*512 -> row = idx>>2 (r0, r0+128), phys chunk = t&3
    const int r0 = t >> 2;
    const int c0 = (t & 3) ^ (r0 & 3);       // inverse-swizzled global chunk
    const u16* Ag = A + (size_t)(m0 + r0) * K + c0 * 8;
    const u16* Bg = E + (size_t)(n0 + r0) * K + c0 * 8;

    // swizzled ds_read chunk offset (u16 units within a 32-u16 row)
    const int rdsw = (kg ^ (lr & 3)) * 8;

    f32x4 acc[8][4];
#pragma unroll
    for (int i = 0; i < 8; ++i)
#pragma unroll
        for (int j = 0; j < 4; ++j) acc[i][j] = (f32x4){0.f, 0.f, 0.f, 0.f};

#define STG_A(sl, kt)                                                       \
    do {                                                                    \
        gl_lds16(Ag + (size_t)(kt) * 32, &As[sl][t * 8]);                   \
        gl_lds16(Ag + (size_t)128 * K + (size_t)(kt) * 32,                  \
                 &As[sl][(t + 512) * 8]);                                   \
    } while (0)
#define STG_B(sl, kt)                                                       \
    do {                                                                    \
        gl_lds16(Bg + (size_t)(kt) * 32, &Bs[sl][t * 8]);                   \
        gl_lds16(Bg + (size_t)128 * K + (size_t)(kt) * 32,                  \
                 &Bs[sl][(t + 512) * 8]);                                   \
    } while (0)

    // prologue: stage tiles 0,1,2 into slots 0,1,2 (12 loads outstanding)
#pragma unroll
    for (int p = 0; p < 3; ++p) { STG_A(p, p); STG_B(p, p); }

#pragma unroll 1
    for (int v = 0; v < NT; ++v) {
        const int sl  = v & 3;
        const int psl = (v + 3) & 3;                 // slot of tile v-1 (done)
        const int vv  = (v + 3 < NT) ? v + 3 : NT - 1;  // clamped tail stage

        __builtin_amdgcn_s_barrier();   // all waves done reading slot psl
        __builtin_amdgcn_sched_barrier(0);

        STG_A(psl, vv);
        asm volatile("s_waitcnt vmcnt(10)" ::: "memory");  // tile v landed (own)
        __builtin_amdgcn_s_barrier();   // tile v landed for ALL waves
        __builtin_amdgcn_sched_barrier(0);

        const u16* __restrict__ as = As[sl];
        const u16* __restrict__ bs = Bs[sl];

        s16x8 av[8], b0, b1;
#pragma unroll
        for (int mi = 0; mi < 8; ++mi)
            av[mi] = *(const s16x8*)&as[(wm * 128 + mi * 16 + lr) * 32 + rdsw];
        b0 = *(const s16x8*)&bs[(wn * 64 + 0 * 16 + lr) * 32 + rdsw];
        b1 = *(const s16x8*)&bs[(wn * 64 + 1 * 16 + lr) * 32 + rdsw];
        __builtin_amdgcn_s_setprio(1);
#pragma unroll
        for (int mi = 0; mi < 8; ++mi) {
            acc[mi][0] = __builtin_amdgcn_mfma_f32_16x16x32_bf16(av[mi], b0, acc[mi][0], 0, 0, 0);
            acc[mi][1] = __builtin_amdgcn_mfma_f32_16x16x32_bf16(av[mi], b1, acc[mi][1], 0, 0, 0);
        }
        __builtin_amdgcn_s_setprio(0);

        STG_B(psl, vv);
        b0 = *(const s16x8*)&bs[(wn * 64 + 2 * 16 + lr) * 32 + rdsw];
        b1 = *(const s16x8*)&bs[(wn * 64 + 3 * 16 + lr) * 32 + rdsw];
        __builtin_amdgcn_s_setprio(1);
#pragma unroll
        for (int mi = 0; mi < 8; ++mi) {
            acc[mi][2] = __builtin_amdgcn_mfma_f32_16x16x32_bf16(av[mi], b0, acc[mi][2], 0, 0, 0);
            acc[mi][3] = __builtin_amdgcn_mfma_f32_16x16x32_bf16(av[mi], b1, acc[mi][3], 0, 0, 0);
        }
        __builtin_amdgcn_s_setprio(0);
    }
#undef STG_A
#undef STG_B

    // epilogue
#pragma unroll
    for (int ni = 0; ni < 4; ++ni) {
        int n = n0 + wn * 64 + ni * 16 + lr;
        float bvl = bias[n];
#pragma unroll
        for (int mi = 0; mi < 8; ++mi) {
#pragma unroll
            for (int r = 0; r < 4; ++r) {
                int m = m0 + wm * 128 + mi * 16 + kg * 4 + r;
                float val = acc[mi][ni][r] + bvl;
                if constexpr (OUTMODE == 0) {
                    ((u16*)outp)[(size_t)m * 2048 + n] = f2bf(val);
                } else if constexpr (OUTMODE == 1) {
                    ((float*)outp)[(size_t)m * 2048 + n] = val;
                } else {
                    int b = m >> 11, s = m & 2047;
                    ((u16*)outp)[((size_t)b * 2048 + n) * 2048 + s] = f2bf(val);
                }
            }
        }
    }
}

// ---------------------------------------------------------------------------
// In-place radix-2 DIT FFT, 2048 complex in padded LDS (input bit-reversed).
// ---------------------------------------------------------------------------
__device__ __forceinline__ void bfly(float* re, float* im, int i0, int i1,
                                     float wr, float wi) {
    int p0 = PD(i0), p1 = PD(i1);
    float xr = re[p1], xi = im[p1];
    float tr = wr * xr - wi * xi;
    float ti = wr * xi + wi * xr;
    float yr = re[p0], yi = im[p0];
    re[p1] = yr - tr; im[p1] = yi - ti;
    re[p0] = yr + tr; im[p0] = yi + ti;
}

__device__ void fft2048(float* re, float* im, int t) {
#pragma unroll 1
    for (int lh = 0; lh < 9; ++lh) {
        const int half = 1 << lh;
        int j = t & (half - 1);
        float wr, wi;
        __sincosf((-PI_F / (float)half) * (float)j, &wi, &wr);
        __syncthreads();
#pragma unroll
        for (int u = 0; u < 4; ++u) {
            int bidx = t + u * 256;
            int i0 = ((bidx >> lh) << (lh + 1)) | j;
            bfly(re, im, i0, i0 + half, wr, wi);
        }
    }
#pragma unroll 1
    for (int lh = 9; lh < 11; ++lh) {
        const int half = 1 << lh;
        __syncthreads();
#pragma unroll
        for (int u = 0; u < 4; ++u) {
            int bidx = t + u * 256;
            int j = bidx & (half - 1);
            int i0 = ((bidx >> lh) << (lh + 1)) | j;
            float wr, wi;
            __sincosf((-PI_F / (float)half) * (float)j, &wi, &wr);
            bfly(re, im, i0, i0 + half, wr, wi);
        }
    }
    __syncthreads();
}

// ---------------------------------------------------------------------------
// Spectral attention: 2 channels/block, Q+iK packed forward FFTs (2),
// Hermitian-packed inverse (1). Vt multiplied in place.
// ---------------------------------------------------------------------------
__global__ __launch_bounds__(256) void spectral2(const u16* __restrict__ Qt,
                                                 const u16* __restrict__ Kt,
                                                 u16* __restrict__ Vt,
                                                 const float* __restrict__ alpha) {
    __shared__ float zre[2112], zim[2112];
    const int t  = threadIdx.x;
    const int b  = blockIdx.x >> 10;
    const int cp = blockIdx.x & 1023;
    const int c0 = cp * 2;
    const size_t base0 = ((size_t)b * 2048 + c0) * 2048;
    const size_t base1 = base0 + 2048;

    float ph[4];
    float PH1r[4], PH1i[4], PH2r[4], PH2i[4];
    float ph24 = 0.f, PH24_1 = 0.f, PH24_2 = 0.f;

#pragma unroll
    for (int ch = 0; ch < 2; ++ch) {
        const size_t base = ch ? base1 : base0;
        const u16* Qp = Qt + base;
        const u16* Kp = Kt + base;
        __syncthreads();
#pragma unroll
        for (int u = 0; u < 8; ++u) {
            int s = t + u * 256;
            int r = __brev((unsigned)s) >> 21;
            zre[PD(r)] = bf2f(Qp[s]);
            zim[PD(r)] = bf2f(Kp[s]);
        }
        fft2048(zre, zim, t);
        const float ac = alpha[c0 + ch];
#pragma unroll
        for (int u = 0; u < 4; ++u) {
            int k = t + u * 256;
            int m = (2048 - k) & 2047;
            float ar = zre[PD(k)], ai = zim[PD(k)];
            float br = zre[PD(m)], bi = zim[PD(m)];
            float qr = 0.5f * (ar + br), qi = 0.5f * (ai - bi);
            float kr = 0.5f * (ai + bi), ki = 0.5f * (br - ar);
            float cr = qr * kr + qi * ki;
            float ci = qi * kr - qr * ki;
            if (ch == 0) {
                int kk = min(k, 2048 - k);
                ph[u] = atanf(__logf((float)kk * (1.0f / 2048.0f) + 1e-6f));
            }
            float fr, fi;
            __sincosf(ph[u] * ac, &fi, &fr);
            float Pkr = cr * fr - ci * fi, Pki = cr * fi + ci * fr;
            float qr2 = 0.5f * (br + ar), qi2 = 0.5f * (bi - ai);
            float kr2 = 0.5f * (bi + ai), ki2 = 0.5f * (ar - br);
            float cr2 = qr2 * kr2 + qi2 * ki2;
            float ci2 = qi2 * kr2 - qr2 * ki2;
            float Pmr = cr2 * fr - ci2 * fi, Pmi = cr2 * fi + ci2 * fr;
            float hr = 0.5f * (Pkr + Pmr), hi = 0.5f * (Pki - Pmi);
            if (ch == 0) { PH1r[u] = hr; PH1i[u] = hi; }
            else         { PH2r[u] = hr; PH2i[u] = hi; }
        }
        if (t == 0) {
            float ar = zre[PD(1024)], ai = zim[PD(1024)];
            float cr = ar * ai;
            if (ch == 0) ph24 = atanf(__logf(0.5f + 1e-6f));
            float fr, fi;
            __sincosf(ph24 * ac, &fi, &fr);
            if (ch == 0) PH24_1 = cr * fr; else PH24_2 = cr * fr;
        }
    }

    __syncthreads();
#pragma unroll
    for (int u = 0; u < 4; ++u) {
        int k = t + u * 256;
        int m = (2048 - k) & 2047;
        int rk = __brev((unsigned)k) >> 21;
        int rm = __brev((unsigned)m) >> 21;
        zre[PD(rk)] = PH1r[u] - PH2i[u];
        zim[PD(rk)] = PH1i[u] + PH2r[u];
        zre[PD(rm)] = PH1r[u] + PH2i[u];
        zim[PD(rm)] = PH2r[u] - PH1i[u];
    }
    if (t == 0) {
        zre[PD(1)] = PH24_1;
        zim[PD(1)] = PH24_2;
    }
    fft2048(zre, zim, t);

#pragma unroll
    for (int u = 0; u < 8; ++u) {
        int s = t + u * 256;
        int j = (2048 - s) & 2047;
        float w0 = zre[PD(j)] * (1.0f / 2048.0f);
        float w1 = zim[PD(j)] * (1.0f / 2048.0f);
        Vt[base0 + s] = f2bf(bf2f(Vt[base0 + s]) * w0);
        Vt[base1 + s] = f2bf(bf2f(Vt[base1 + s]) * w1);
    }
}

// ---------------------------------------------------------------------------
// Transpose [B][C][S] bf16 -> [(b,s)][c] bf16
// ---------------------------------------------------------------------------
__global__ __launch_bounds__(256) void transpose_k(const u16* __restrict__ in,
                                                   u16* __restrict__ out) {
    __shared__ u16 tile[32][33];
    int b = blockIdx.z;
    int c0 = blockIdx.x * 32, s0 = blockIdx.y * 32;
    int tx = threadIdx.x, ty = threadIdx.y;
#pragma unroll
    for (int dy = 0; dy < 32; dy += 8)
        tile[ty + dy][tx] = in[((size_t)b * 2048 + c0 + ty + dy) * 2048 + s0 + tx];
    __syncthreads();
#pragma unroll
    for (int dy = 0; dy < 32; dy += 8)
        out[((size_t)b * 2048 + s0 + ty + dy) * 2048 + c0 + tx] = tile[tx][ty + dy];
}

// ---------------------------------------------------------------------------
extern "C" void kernel_launch(void* const* d_in, const int* in_sizes, int n_in,
                              void* d_out, int out_size, void* d_ws, size_t ws_size,
                              hipStream_t stream) {
    const float* query = (const float*)d_in[0];
    const float* key   = (const float*)d_in[1];
    const float* value = (const float*)d_in[2];
    const float* Wq    = (const float*)d_in[3];
    const float* bq    = (const float*)d_in[4];
    const float* Wk    = (const float*)d_in[5];
    const float* bk    = (const float*)d_in[6];
    const float* Wv    = (const float*)d_in[7];
    const float* bv    = (const float*)d_in[8];
    const float* alpha = (const float*)d_in[9];
    const float* Wint  = (const float*)d_in[10];
    const float* bint  = (const float*)d_in[11];
    const float* Wfin  = (const float*)d_in[12];
    const float* bfin  = (const float*)d_in[13];
    const float* Wout  = (const float*)d_in[14];
    const float* bout  = (const float*)d_in[15];

    char* ws = (char*)d_ws;
    size_t off = 0;
    auto alloc = [&](size_t bytes) -> void* {
        void* p = ws + off;
        off += (bytes + 255) & ~(size_t)255;
        return p;
    };
    u16* Eq   = (u16*)alloc((size_t)2048 * 512 * 2);
    u16* Ek   = (u16*)alloc((size_t)2048 * 512 * 2);
    u16* Ev   = (u16*)alloc((size_t)2048 * 512 * 2);
    u16* Eint = (u16*)alloc((size_t)2048 * 2048 * 2);
    u16* Efin = (u16*)alloc((size_t)2048 * 2048 * 2);
    u16* Eout = (u16*)alloc((size_t)2048 * 2048 * 2);
    u16* Qt   = (u16*)alloc((size_t)4 * 2048 * 2048 * 2);  // [B][C][S]
    u16* Kt   = (u16*)alloc((size_t)4 * 2048 * 2048 * 2);
    u16* Vt   = (u16*)alloc((size_t)4 * 2048 * 2048 * 2);
    u16* attn = (u16*)alloc((size_t)8192 * 2048 * 2);
    u16* h1   = Qt;
    u16* h2   = Kt;
    u16* Aq = attn;
    u16* Ak = attn + (size_t)8192 * 512;
    u16* Av = attn + (size_t)8192 * 1024;

    const int n8 = 8192 * 512 / 8;
    cvt_bf16<<<(n8 + 255) / 256, 256, 0, stream>>>(query, Aq, n8);
    cvt_bf16<<<(n8 + 255) / 256, 256, 0, stream>>>(key,   Ak, n8);
    cvt_bf16<<<(n8 + 255) / 256, 256, 0, stream>>>(value, Av, n8);

    build_E<<<(2048 * 512  + 255) / 256, 256, 0, stream>>>(Wq,   Eq,   9);
    build_E<<<(2048 * 512  + 255) / 256, 256, 0, stream>>>(Wk,   Ek,   9);
    build_E<<<(2048 * 512  + 255) / 256, 256, 0, stream>>>(Wv,   Ev,   9);
    build_E<<<(2048 * 2048 + 255) / 256, 256, 0, stream>>>(Wint, Eint, 11);
    build_E<<<(2048 * 2048 + 255) / 256, 256, 0, stream>>>(Wfin, Efin, 11);
    build_E<<<(2048 * 2048 + 255) / 256, 256, 0, stream>>>(Wout, Eout, 11);

    dim3 g4(8, 32);   // N/256, M/256
    gemm4<512, 2><<<g4, 512, 0, stream>>>(Aq, Eq, bq, Qt);
    gemm4<512, 2><<<g4, 512, 0, stream>>>(Ak, Ek, bk, Kt);
    gemm4<512, 2><<<g4, 512, 0, stream>>>(Av, Ev, bv, Vt);

    spectral2<<<4096, 256, 0, stream>>>(Qt, Kt, Vt, alpha);

    dim3 gt(64, 64, 4);
    transpose_k<<<gt, dim3(32, 8), 0, stream>>>(Vt, attn);

    gemm4<2048, 0><<<g4, 512, 0, stream>>>(attn, Eint, bint, h1);
    gemm4<2048, 0><<<g4, 512, 0, stream>>>(h1,   Efin, bfin, h2);
    gemm4<2048, 1><<<g4, 512, 0, stream>>>(h2,   Eout, bout, (float*)d_out);
}

// Round 6
// 498.234 us; speedup vs baseline: 1.2130x; 1.1491x over previous
//
#include <hip/hip_runtime.h>
#include <hip/hip_bf16.h>
#include <cstdint>

typedef unsigned short u16;
typedef u16  u16x8 __attribute__((ext_vector_type(8)));
typedef short s16x8 __attribute__((ext_vector_type(8)));
typedef float f32x4 __attribute__((ext_vector_type(4)));

#define PI_F 3.14159265358979323846f
#define PD(i) ((i) + ((i) >> 5))

static __device__ __forceinline__ u16 f2bf(float f) {
    union { float f; unsigned u; } v; v.f = f;
    unsigned r = v.u + 0x7fffu + ((v.u >> 16) & 1u);
    return (u16)(r >> 16);
}
static __device__ __forceinline__ float bf2f(u16 h) {
    union { unsigned u; float f; } v; v.u = ((unsigned)h) << 16;
    return v.f;
}

__device__ __forceinline__ void gl_lds16(const u16* g, u16* l) {
    __builtin_amdgcn_global_load_lds(
        (const __attribute__((address_space(1))) unsigned int*)g,
        (__attribute__((address_space(3))) unsigned int*)l, 16, 0, 0);
}

// ---------------------------------------------------------------------------
// f32 -> bf16 convert (vectorized)
// ---------------------------------------------------------------------------
__global__ __launch_bounds__(256) void cvt_bf16(const float* __restrict__ in,
                                                u16* __restrict__ out, int n8) {
    int i = blockIdx.x * 256 + threadIdx.x;
    if (i >= n8) return;
    float4 a = ((const float4*)in)[2 * i];
    float4 b = ((const float4*)in)[2 * i + 1];
    u16x8 v;
    v[0] = f2bf(a.x); v[1] = f2bf(a.y); v[2] = f2bf(a.z); v[3] = f2bf(a.w);
    v[4] = f2bf(b.x); v[5] = f2bf(b.y); v[6] = f2bf(b.z); v[7] = f2bf(b.w);
    ((u16x8*)out)[i] = v;
}

// ---------------------------------------------------------------------------
// Expand quaternion weight W[4][512][in_q] into real matrix E[2048][4*in_q] bf16
// ---------------------------------------------------------------------------
__global__ void build_E(const float* __restrict__ W, u16* __restrict__ E, int logK) {
    const int K = 1 << logK;
    int idx = blockIdx.x * 256 + threadIdx.x;
    if (idx >= (2048 << logK)) return;
    int n = idx >> logK, k = idx & (K - 1);
    int o = n >> 2, c = n & 3, i = k >> 2, cp = k & 3;
    const int   qm[4][4] = {{0,1,2,3},{1,0,3,2},{2,3,0,1},{3,2,1,0}};
    const float qs[4][4] = {{1.f,-1.f,-1.f,-1.f},{1.f,1.f,1.f,-1.f},
                            {1.f,-1.f,1.f,1.f},{1.f,1.f,-1.f,1.f}};
    int in_q = K >> 2;
    float w = W[(size_t)qm[c][cp] * 512 * in_q + (size_t)o * in_q + i] * qs[c][cp];
    E[idx] = f2bf(w);
}

// ---------------------------------------------------------------------------
// bf16 MFMA GEMM (m97 structure, PROVEN R2): out = A[M][K] * E[N][K]^T + bias
// 128x128 tile, BK=64, 4 waves (2x2), each wave 64x64 = 4x4 frags 16x16x32.
// global_load_lds 16B direct staging; T2 swizzle slot^=row&7 both sides.
// OUTMODE 0: bf16 [m][n]; 1: f32 [m][n]; 2: bf16 transposed [b][n][s]
// ---------------------------------------------------------------------------
template<int K, int OUTMODE>
__global__ __launch_bounds__(256) void gemm2(const u16* __restrict__ A,
                                             const u16* __restrict__ E,
                                             const float* __restrict__ bias,
                                             void* __restrict__ outp) {
    __shared__ u16 As[128 * 64];
    __shared__ u16 Bs[128 * 64];
    const int t    = threadIdx.x;
    const int lane = t & 63, wave = t >> 6;
    const int wr   = wave >> 1, wc = wave & 1;
    const int lr   = lane & 15, kg = lane >> 4;
    const int l7   = lr & 7;
    const int m0   = blockIdx.y * 128;
    const int n0   = blockIdx.x * 128;

    f32x4 acc[4][4];
#pragma unroll
    for (int i = 0; i < 4; ++i)
#pragma unroll
        for (int j = 0; j < 4; ++j) acc[i][j] = (f32x4){0.f, 0.f, 0.f, 0.f};

    const int arow = wr * 64 + lr;
    const int brow = wc * 64 + lr;

    for (int k0 = 0; k0 < K; k0 += 64) {
#pragma unroll
        for (int c = 0; c < 4; ++c) {
            int idx = t + c * 256;
            int row = idx >> 3, sl = idx & 7;
            int gsl = sl ^ (row & 7);          // inverse-swizzled global source
            gl_lds16(A + (size_t)(m0 + row) * K + k0 + gsl * 8, &As[idx * 8]);
            gl_lds16(E + (size_t)(n0 + row) * K + k0 + gsl * 8, &Bs[idx * 8]);
        }
        __syncthreads();
#pragma unroll
        for (int ks = 0; ks < 2; ++ks) {
            const int slot = (ks * 4 + kg) ^ l7;   // swizzled read slot
            s16x8 av[4], bv[4];
#pragma unroll
            for (int mi = 0; mi < 4; ++mi)
                av[mi] = *(const s16x8*)&As[(arow + mi * 16) * 64 + slot * 8];
#pragma unroll
            for (int ni = 0; ni < 4; ++ni)
                bv[ni] = *(const s16x8*)&Bs[(brow + ni * 16) * 64 + slot * 8];
#pragma unroll
            for (int mi = 0; mi < 4; ++mi)
#pragma unroll
                for (int ni = 0; ni < 4; ++ni)
                    acc[mi][ni] = __builtin_amdgcn_mfma_f32_16x16x32_bf16(
                        av[mi], bv[ni], acc[mi][ni], 0, 0, 0);
        }
        __syncthreads();
    }

#pragma unroll
    for (int ni = 0; ni < 4; ++ni) {
        int n = n0 + wc * 64 + ni * 16 + lr;
        float bvl = bias[n];
#pragma unroll
        for (int mi = 0; mi < 4; ++mi) {
#pragma unroll
            for (int r = 0; r < 4; ++r) {
                int m = m0 + wr * 64 + mi * 16 + kg * 4 + r;
                float val = acc[mi][ni][r] + bvl;
                if constexpr (OUTMODE == 0) {
                    ((u16*)outp)[(size_t)m * 2048 + n] = f2bf(val);
                } else if constexpr (OUTMODE == 1) {
                    ((float*)outp)[(size_t)m * 2048 + n] = val;
                } else {
                    int b = m >> 11, s = m & 2047;
                    ((u16*)outp)[((size_t)b * 2048 + n) * 2048 + s] = f2bf(val);
                }
            }
        }
    }
}

// ---------------------------------------------------------------------------
// In-place FFT over 2048 complex points in padded LDS, bit-reversed input,
// natural output. Radix-4 fused passes (stage pairs 0-9) + final radix-2.
// Identical stage sequence to radix-2 DIT -> same I/O convention as before.
// ---------------------------------------------------------------------------
__device__ __forceinline__ void bfly(float* re, float* im, int i0, int i1,
                                     float wr, float wi) {
    int p0 = PD(i0), p1 = PD(i1);
    float xr = re[p1], xi = im[p1];
    float tr = wr * xr - wi * xi;
    float ti = wr * xi + wi * xr;
    float yr = re[p0], yi = im[p0];
    re[p1] = yr - tr; im[p1] = yi - ti;
    re[p0] = yr + tr; im[p0] = yi + ti;
}

__device__ void fft2048(float* re, float* im, int t) {
#pragma unroll 1
    for (int lh = 0; lh < 10; lh += 2) {
        const int h = 1 << lh;
        const int j = t & (h - 1);           // u-invariant for h<=256
        float w2r, w2i;
        __sincosf((-PI_F / (float)(2 * h)) * (float)j, &w2i, &w2r);
        const float w1r = w2r * w2r - w2i * w2i;
        const float w1i = 2.f * w2r * w2i;
        const float w3r = w2i, w3i = -w2r;   // -i * W2
        __syncthreads();
#pragma unroll
        for (int u = 0; u < 2; ++u) {
            int vidx = t + u * 256;          // 0..511 radix-4 butterflies
            int i0 = ((vidx >> lh) << (lh + 2)) | j;
            int p0 = PD(i0), p1 = PD(i0 + h), p2 = PD(i0 + 2 * h), p3 = PD(i0 + 3 * h);
            float ar = re[p0], ai = im[p0];
            float br = re[p1], bi = im[p1];
            float cr = re[p2], ci = im[p2];
            float dr = re[p3], di = im[p3];
            // stage lh (half=h): (a,b) and (c,d) with W1
            float tbr = w1r * br - w1i * bi, tbi = w1r * bi + w1i * br;
            float tdr = w1r * dr - w1i * di, tdi = w1r * di + w1i * dr;
            float a1r = ar + tbr, a1i = ai + tbi;
            float b1r = ar - tbr, b1i = ai - tbi;
            float c1r = cr + tdr, c1i = ci + tdi;
            float d1r = cr - tdr, d1i = ci - tdi;
            // stage lh+1 (half=2h): (a1,c1) with W2, (b1,d1) with W3=-i*W2
            float tcr = w2r * c1r - w2i * c1i, tci = w2r * c1i + w2i * c1r;
            float ter = w3r * d1r - w3i * d1i, tei = w3r * d1i + w3i * d1r;
            re[p0] = a1r + tcr; im[p0] = a1i + tci;
            re[p2] = a1r - tcr; im[p2] = a1i - tci;
            re[p1] = b1r + ter; im[p1] = b1i + tei;
            re[p3] = b1r - ter; im[p3] = b1i - tei;
        }
    }
    // final radix-2 stage, half = 1024
    __syncthreads();
#pragma unroll
    for (int u = 0; u < 4; ++u) {
        int j = t + u * 256;
        float wr, wi;
        __sincosf((-PI_F / 1024.0f) * (float)j, &wi, &wr);
        bfly(re, im, j, j + 1024, wr, wi);
    }
    __syncthreads();
}

// ---------------------------------------------------------------------------
// Spectral attention: 2 channels/block, Q+iK packed forward FFTs (2),
// Hermitian-packed inverse (1). Vt multiplied in place.
// ---------------------------------------------------------------------------
__global__ __launch_bounds__(256) void spectral2(const u16* __restrict__ Qt,
                                                 const u16* __restrict__ Kt,
                                                 u16* __restrict__ Vt,
                                                 const float* __restrict__ alpha) {
    __shared__ float zre[2112], zim[2112];
    const int t  = threadIdx.x;
    const int b  = blockIdx.x >> 10;
    const int cp = blockIdx.x & 1023;
    const int c0 = cp * 2;
    const size_t base0 = ((size_t)b * 2048 + c0) * 2048;
    const size_t base1 = base0 + 2048;

    float ph[4];
    float PH1r[4], PH1i[4], PH2r[4], PH2i[4];
    float ph24 = 0.f, PH24_1 = 0.f, PH24_2 = 0.f;

#pragma unroll
    for (int ch = 0; ch < 2; ++ch) {
        const size_t base = ch ? base1 : base0;
        const u16* Qp = Qt + base;
        const u16* Kp = Kt + base;
        __syncthreads();
#pragma unroll
        for (int u = 0; u < 8; ++u) {
            int s = t + u * 256;
            int r = __brev((unsigned)s) >> 21;
            zre[PD(r)] = bf2f(Qp[s]);
            zim[PD(r)] = bf2f(Kp[s]);
        }
        fft2048(zre, zim, t);
        const float ac = alpha[c0 + ch];
#pragma unroll
        for (int u = 0; u < 4; ++u) {
            int k = t + u * 256;
            int m = (2048 - k) & 2047;
            float ar = zre[PD(k)], ai = zim[PD(k)];
            float br = zre[PD(m)], bi = zim[PD(m)];
            float qr = 0.5f * (ar + br), qi = 0.5f * (ai - bi);
            float kr = 0.5f * (ai + bi), ki = 0.5f * (br - ar);
            float cr = qr * kr + qi * ki;
            float ci = qi * kr - qr * ki;
            if (ch == 0) {
                int kk = min(k, 2048 - k);
                ph[u] = atanf(__logf((float)kk * (1.0f / 2048.0f) + 1e-6f));
            }
            float fr, fi;
            __sincosf(ph[u] * ac, &fi, &fr);
            float Pkr = cr * fr - ci * fi, Pki = cr * fi + ci * fr;
            float qr2 = 0.5f * (br + ar), qi2 = 0.5f * (bi - ai);
            float kr2 = 0.5f * (bi + ai), ki2 = 0.5f * (ar - br);
            float cr2 = qr2 * kr2 + qi2 * ki2;
            float ci2 = qi2 * kr2 - qr2 * ki2;
            float Pmr = cr2 * fr - ci2 * fi, Pmi = cr2 * fi + ci2 * fr;
            float hr = 0.5f * (Pkr + Pmr), hi = 0.5f * (Pki - Pmi);
            if (ch == 0) { PH1r[u] = hr; PH1i[u] = hi; }
            else         { PH2r[u] = hr; PH2i[u] = hi; }
        }
        if (t == 0) {
            float ar = zre[PD(1024)], ai = zim[PD(1024)];
            float cr = ar * ai;
            if (ch == 0) ph24 = atanf(__logf(0.5f + 1e-6f));
            float fr, fi;
            __sincosf(ph24 * ac, &fi, &fr);
            if (ch == 0) PH24_1 = cr * fr; else PH24_2 = cr * fr;
        }
    }

    __syncthreads();
#pragma unroll
    for (int u = 0; u < 4; ++u) {
        int k = t + u * 256;
        int m = (2048 - k) & 2047;
        int rk = __brev((unsigned)k) >> 21;
        int rm = __brev((unsigned)m) >> 21;
        zre[PD(rk)] = PH1r[u] - PH2i[u];
        zim[PD(rk)] = PH1i[u] + PH2r[u];
        zre[PD(rm)] = PH1r[u] + PH2i[u];
        zim[PD(rm)] = PH2r[u] - PH1i[u];
    }
    if (t == 0) {
        zre[PD(1)] = PH24_1;
        zim[PD(1)] = PH24_2;
    }
    fft2048(zre, zim, t);

#pragma unroll
    for (int u = 0; u < 8; ++u) {
        int s = t + u * 256;
        int j = (2048 - s) & 2047;
        float w0 = zre[PD(j)] * (1.0f / 2048.0f);
        float w1 = zim[PD(j)] * (1.0f / 2048.0f);
        Vt[base0 + s] = f2bf(bf2f(Vt[base0 + s]) * w0);
        Vt[base1 + s] = f2bf(bf2f(Vt[base1 + s]) * w1);
    }
}

// ---------------------------------------------------------------------------
// Transpose [B][C][S] bf16 -> [(b,s)][c] bf16
// ---------------------------------------------------------------------------
__global__ __launch_bounds__(256) void transpose_k(const u16* __restrict__ in,
                                                   u16* __restrict__ out) {
    __shared__ u16 tile[32][33];
    int b = blockIdx.z;
    int c0 = blockIdx.x * 32, s0 = blockIdx.y * 32;
    int tx = threadIdx.x, ty = threadIdx.y;
#pragma unroll
    for (int dy = 0; dy < 32; dy += 8)
        tile[ty + dy][tx] = in[((size_t)b * 2048 + c0 + ty + dy) * 2048 + s0 + tx];
    __syncthreads();
#pragma unroll
    for (int dy = 0; dy < 32; dy += 8)
        out[((size_t)b * 2048 + s0 + ty + dy) * 2048 + c0 + tx] = tile[tx][ty + dy];
}

// ---------------------------------------------------------------------------
extern "C" void kernel_launch(void* const* d_in, const int* in_sizes, int n_in,
                              void* d_out, int out_size, void* d_ws, size_t ws_size,
                              hipStream_t stream) {
    const float* query = (const float*)d_in[0];
    const float* key   = (const float*)d_in[1];
    const float* value = (const float*)d_in[2];
    const float* Wq    = (const float*)d_in[3];
    const float* bq    = (const float*)d_in[4];
    const float* Wk    = (const float*)d_in[5];
    const float* bk    = (const float*)d_in[6];
    const float* Wv    = (const float*)d_in[7];
    const float* bv    = (const float*)d_in[8];
    const float* alpha = (const float*)d_in[9];
    const float* Wint  = (const float*)d_in[10];
    const float* bint  = (const float*)d_in[11];
    const float* Wfin  = (const float*)d_in[12];
    const float* bfin  = (const float*)d_in[13];
    const float* Wout  = (const float*)d_in[14];
    const float* bout  = (const float*)d_in[15];

    char* ws = (char*)d_ws;
    size_t off = 0;
    auto alloc = [&](size_t bytes) -> void* {
        void* p = ws + off;
        off += (bytes + 255) & ~(size_t)255;
        return p;
    };
    u16* Eq   = (u16*)alloc((size_t)2048 * 512 * 2);
    u16* Ek   = (u16*)alloc((size_t)2048 * 512 * 2);
    u16* Ev   = (u16*)alloc((size_t)2048 * 512 * 2);
    u16* Eint = (u16*)alloc((size_t)2048 * 2048 * 2);
    u16* Efin = (u16*)alloc((size_t)2048 * 2048 * 2);
    u16* Eout = (u16*)alloc((size_t)2048 * 2048 * 2);
    u16* Qt   = (u16*)alloc((size_t)4 * 2048 * 2048 * 2);  // [B][C][S]
    u16* Kt   = (u16*)alloc((size_t)4 * 2048 * 2048 * 2);
    u16* Vt   = (u16*)alloc((size_t)4 * 2048 * 2048 * 2);
    u16* attn = (u16*)alloc((size_t)8192 * 2048 * 2);
    u16* h1   = Qt;
    u16* h2   = Kt;
    u16* Aq = attn;
    u16* Ak = attn + (size_t)8192 * 512;
    u16* Av = attn + (size_t)8192 * 1024;

    const int n8 = 8192 * 512 / 8;
    cvt_bf16<<<(n8 + 255) / 256, 256, 0, stream>>>(query, Aq, n8);
    cvt_bf16<<<(n8 + 255) / 256, 256, 0, stream>>>(key,   Ak, n8);
    cvt_bf16<<<(n8 + 255) / 256, 256, 0, stream>>>(value, Av, n8);

    build_E<<<(2048 * 512  + 255) / 256, 256, 0, stream>>>(Wq,   Eq,   9);
    build_E<<<(2048 * 512  + 255) / 256, 256, 0, stream>>>(Wk,   Ek,   9);
    build_E<<<(2048 * 512  + 255) / 256, 256, 0, stream>>>(Wv,   Ev,   9);
    build_E<<<(2048 * 2048 + 255) / 256, 256, 0, stream>>>(Wint, Eint, 11);
    build_E<<<(2048 * 2048 + 255) / 256, 256, 0, stream>>>(Wfin, Efin, 11);
    build_E<<<(2048 * 2048 + 255) / 256, 256, 0, stream>>>(Wout, Eout, 11);

    dim3 g2(16, 64);   // N/128, M/128
    gemm2<512, 2><<<g2, 256, 0, stream>>>(Aq, Eq, bq, Qt);
    gemm2<512, 2><<<g2, 256, 0, stream>>>(Ak, Ek, bk, Kt);
    gemm2<512, 2><<<g2, 256, 0, stream>>>(Av, Ev, bv, Vt);

    spectral2<<<4096, 256, 0, stream>>>(Qt, Kt, Vt, alpha);

    dim3 gt(64, 64, 4);
    transpose_k<<<gt, dim3(32, 8), 0, stream>>>(Vt, attn);

    gemm2<2048, 0><<<g2, 256, 0, stream>>>(attn, Eint, bint, h1);
    gemm2<2048, 0><<<g2, 256, 0, stream>>>(h1,   Efin, bfin, h2);
    gemm2<2048, 1><<<g2, 256, 0, stream>>>(h2,   Eout, bout, (float*)d_out);
}